// Round 3
// baseline (337.830 us; speedup 1.0000x reference)
//
#include <hip/hip_runtime.h>

// Problem constants
#define BB 256   // batch
#define HH 512   // hidden
#define CC 64    // spline channels
#define NN 100   // time knots
#define KT 8     // K_TERMS

typedef short s16x8 __attribute__((ext_vector_type(8)));
typedef float f32x4 __attribute__((ext_vector_type(4)));

#define MFMA16(a, b, c) __builtin_amdgcn_mfma_f32_16x16x32_bf16((a), (b), (c), 0, 0, 0)

static __device__ __forceinline__ unsigned short f2bf(float f) {
    union { float f; unsigned int u; } v; v.f = f;
    unsigned int r = v.u + 0x7FFFu + ((v.u >> 16) & 1u);  // RNE
    return (unsigned short)(r >> 16);
}

// ---------------------------------------------------------------------------
// A-frag layout for a 16-row x 512-col bf16 activation tile t (8192 halfwords):
//   F[t*8192 + g*512 + lane*8 + e] = M[lane&15][g*32 + (lane>>4)*8 + e]
// MFMA A-operand for Ktile g is a coalesced 16B/lane load at lane*8.
// For K=64 (x/xdot) tiles: 2 g-groups, 1024 halfwords per 16-row tile.
// ---------------------------------------------------------------------------

// ---------------------------------------------------------------------------
// k_pack: weight bf16 conversion into MFMA-frag-packed layout + h conversion
// into A-FRAG layout + cubic spline eval (x, xdot) directly into A-frag.
// ---------------------------------------------------------------------------
__global__ void k_pack(const float* __restrict__ wh, const float* __restrict__ wout,
                       const float* __restrict__ wx, const float* __restrict__ h,
                       const float* __restrict__ coeffs, const float* __restrict__ dcoeffs,
                       const float* __restrict__ tobs, const float* __restrict__ tg,
                       unsigned short* __restrict__ whp, unsigned short* __restrict__ wop,
                       unsigned short* __restrict__ wxp, unsigned short* __restrict__ hf,
                       unsigned short* __restrict__ xf, unsigned short* __restrict__ xdf) {
    int gid = blockIdx.x * 256 + threadIdx.x;
    if (gid < 524288) {                       // wh / wout packed (262144 each)
        const float* src = (gid < 262144) ? wh : wout;
        unsigned short* dst = (gid < 262144) ? whp : wop;
        int p = gid & 262143;
        int e = p & 7, lane = (p >> 3) & 63, g = (p >> 9) & 15, cg = (p >> 13) & 1, w = p >> 14;
        int row = w * 32 + cg * 16 + (lane & 15);
        int k = g * 32 + (lane >> 4) * 8 + e;
        dst[p] = f2bf(src[row * HH + k]);
    } else if (gid < 557056) {                // wx packed (32768)
        int p = gid - 524288;
        int e = p & 7, lane = (p >> 3) & 63, g = (p >> 9) & 1, cg = (p >> 10) & 1, w = p >> 11;
        int row = w * 32 + cg * 16 + (lane & 15);
        int k = g * 32 + (lane >> 4) * 8 + e;
        wxp[p] = f2bf(wx[row * CC + k]);
    } else if (gid < 688128) {                // h -> bf16 A-frag (131072)
        int p = gid - 557056;
        int e = p & 7, lane = (p >> 3) & 63, g = (p >> 9) & 15, btp = p >> 13;
        int row = btp * 16 + (lane & 15);
        int k = g * 32 + (lane >> 4) * 8 + e;
        hf[p] = f2bf(h[row * HH + k]);
    } else if (gid < 704512) {                // spline eval -> A-frag (16384)
        int p = gid - 688128;
        int b = p >> 6, c = p & 63;
        float t = tg[0];
        int cntv = 0;
        for (int n = 0; n < NN; n++) cntv += (tobs[n] <= t) ? 1 : 0;
        int idx = cntv - 1;
        idx = idx < 0 ? 0 : (idx > NN - 2 ? NN - 2 : idx);  // clip to [0, 98]
        float dt = t - tobs[idx];
        const float* cb = coeffs + ((size_t)(b * (NN - 1) + idx) * 4) * CC + c;
        float xv = cb[0] + dt * (cb[CC] + dt * (cb[2 * CC] + dt * cb[3 * CC]));
        const float* db = dcoeffs + ((size_t)(b * (NN - 1) + idx) * 4) * CC + c;
        float xd = db[0] + dt * (db[CC] + dt * (db[2 * CC] + dt * db[3 * CC]));
        // frag index for M[b&15][c] within tile b>>4 (K=64: 2 g-groups)
        int fi = (b >> 4) * 1024 + (c >> 5) * 512 + ((b & 15) + ((c >> 3) & 3) * 16) * 8 + (c & 7);
        xf[fi] = f2bf(xv);
        xdf[fi] = f2bf(xd);
    }
}

// ---------------------------------------------------------------------------
// k_fused: whole network, 16 blocks x 512 threads (1 block/CU, 2 waves/SIMD).
// Weight residency: K-groups g=13..15 of wh AND wout pinned in VGPRs (24 frags
// = 96 regs/lane), g=12 of both pinned in LDS (64KB); phases stream only
// g=0..11 from L2 (384KB instead of 512KB, -25%). The streamed double-buffer's
// last two refills fetch the NEXT phase's g0/g1 (weights are data-independent)
// so the compiler's vmcnt(0) drain at the barrier completes them for free.
// Pinned groups are computed first after each barrier to hide stream restart.
// ---------------------------------------------------------------------------

// single-A GEMM core over 16 K-groups: 12 streamed (bfr0/bfr1 dbuf) + 4 pinned.
#define CORE1(WL, WLN, P13, P14, P15, WPI, AR) do {                              \
    _Pragma("unroll")                                                            \
    for (int t = 0; t < 4; t++) acc[t] = (f32x4){0.f, 0.f, 0.f, 0.f};            \
    {                                                                            \
        const s16x8 a12 = *(const s16x8*)((AR) + 12 * 512);                      \
        const s16x8 a13 = *(const s16x8*)((AR) + 13 * 512);                      \
        const s16x8 a14 = *(const s16x8*)((AR) + 14 * 512);                      \
        const s16x8 a15 = *(const s16x8*)((AR) + 15 * 512);                      \
        _Pragma("unroll")                                                        \
        for (int t = 0; t < 4; t++) {                                            \
            const s16x8 b12 = *(const s16x8*)&wpin[WPI][((w * 4 + t) * 64 + lane) * 8]; \
            acc[t] = MFMA16(a12, b12, acc[t]);                                   \
            acc[t] = MFMA16(a13, P13[t], acc[t]);                                \
            acc[t] = MFMA16(a14, P14[t], acc[t]);                                \
            acc[t] = MFMA16(a15, P15[t], acc[t]);                                \
        }                                                                        \
    }                                                                            \
    _Pragma("unroll")                                                            \
    for (int g = 0; g < 12; g += 2) {                                            \
        {                                                                        \
            const s16x8 a = *(const s16x8*)((AR) + g * 512);                     \
            _Pragma("unroll")                                                    \
            for (int t = 0; t < 4; t++) acc[t] = MFMA16(a, bfr0[t], acc[t]);     \
            const s16x8* ws = (g < 10) ? (WL) : (WLN);                           \
            const int gg = (g < 10) ? (g + 2) : (g - 10);                        \
            _Pragma("unroll")                                                    \
            for (int t = 0; t < 4; t++) bfr0[t] = ws[t * 1024 + gg * 64];        \
        }                                                                        \
        {                                                                        \
            const s16x8 a = *(const s16x8*)((AR) + (g + 1) * 512);               \
            _Pragma("unroll")                                                    \
            for (int t = 0; t < 4; t++) acc[t] = MFMA16(a, bfr1[t], acc[t]);     \
            const s16x8* ws = (g + 1 < 10) ? (WL) : (WLN);                       \
            const int gg = (g + 1 < 10) ? (g + 3) : (g - 9);                     \
            _Pragma("unroll")                                                    \
            for (int t = 0; t < 4; t++) bfr1[t] = ws[t * 1024 + gg * 64];        \
        }                                                                        \
    }                                                                            \
} while (0)

// dual-A variant (shared B stream): acc from AR, cac from AR2.
#define CORE2(WL, WLN, P13, P14, P15, WPI, AR, AR2) do {                         \
    _Pragma("unroll")                                                            \
    for (int t = 0; t < 4; t++) {                                                \
        acc[t] = (f32x4){0.f, 0.f, 0.f, 0.f};                                    \
        cac[t] = (f32x4){0.f, 0.f, 0.f, 0.f};                                    \
    }                                                                            \
    {                                                                            \
        const s16x8 a12 = *(const s16x8*)((AR) + 12 * 512);                      \
        const s16x8 a13 = *(const s16x8*)((AR) + 13 * 512);                      \
        const s16x8 a14 = *(const s16x8*)((AR) + 14 * 512);                      \
        const s16x8 a15 = *(const s16x8*)((AR) + 15 * 512);                      \
        const s16x8 c12 = *(const s16x8*)((AR2) + 12 * 512);                     \
        const s16x8 c13 = *(const s16x8*)((AR2) + 13 * 512);                     \
        const s16x8 c14 = *(const s16x8*)((AR2) + 14 * 512);                     \
        const s16x8 c15 = *(const s16x8*)((AR2) + 15 * 512);                     \
        _Pragma("unroll")                                                        \
        for (int t = 0; t < 4; t++) {                                            \
            const s16x8 b12 = *(const s16x8*)&wpin[WPI][((w * 4 + t) * 64 + lane) * 8]; \
            acc[t] = MFMA16(a12, b12, acc[t]);                                   \
            cac[t] = MFMA16(c12, b12, cac[t]);                                   \
            acc[t] = MFMA16(a13, P13[t], acc[t]);                                \
            cac[t] = MFMA16(c13, P13[t], cac[t]);                                \
            acc[t] = MFMA16(a14, P14[t], acc[t]);                                \
            cac[t] = MFMA16(c14, P14[t], cac[t]);                                \
            acc[t] = MFMA16(a15, P15[t], acc[t]);                                \
            cac[t] = MFMA16(c15, P15[t], cac[t]);                                \
        }                                                                        \
    }                                                                            \
    _Pragma("unroll")                                                            \
    for (int g = 0; g < 12; g += 2) {                                            \
        {                                                                        \
            const s16x8 a = *(const s16x8*)((AR) + g * 512);                     \
            const s16x8 a2 = *(const s16x8*)((AR2) + g * 512);                   \
            _Pragma("unroll")                                                    \
            for (int t = 0; t < 4; t++) {                                        \
                acc[t] = MFMA16(a, bfr0[t], acc[t]);                             \
                cac[t] = MFMA16(a2, bfr0[t], cac[t]);                            \
            }                                                                    \
            const s16x8* ws = (g < 10) ? (WL) : (WLN);                           \
            const int gg = (g < 10) ? (g + 2) : (g - 10);                        \
            _Pragma("unroll")                                                    \
            for (int t = 0; t < 4; t++) bfr0[t] = ws[t * 1024 + gg * 64];        \
        }                                                                        \
        {                                                                        \
            const s16x8 a = *(const s16x8*)((AR) + (g + 1) * 512);               \
            const s16x8 a2 = *(const s16x8*)((AR2) + (g + 1) * 512);             \
            _Pragma("unroll")                                                    \
            for (int t = 0; t < 4; t++) {                                        \
                acc[t] = MFMA16(a, bfr1[t], acc[t]);                             \
                cac[t] = MFMA16(a2, bfr1[t], cac[t]);                            \
            }                                                                    \
            const s16x8* ws = (g + 1 < 10) ? (WL) : (WLN);                       \
            const int gg = (g + 1 < 10) ? (g + 3) : (g - 9);                     \
            _Pragma("unroll")                                                    \
            for (int t = 0; t < 4; t++) bfr1[t] = ws[t * 1024 + gg * 64];        \
        }                                                                        \
    }                                                                            \
} while (0)

__global__ __launch_bounds__(512, 2) void k_fused(
    const unsigned short* __restrict__ whp, const unsigned short* __restrict__ wop,
    const unsigned short* __restrict__ wxp, const unsigned short* __restrict__ hf,
    const unsigned short* __restrict__ xf, const unsigned short* __restrict__ xdf,
    const float* __restrict__ b0g, const float* __restrict__ b1g,
    float* __restrict__ outp) {
    __shared__ __align__(16) unsigned short sa[2][8192];    // ping-pong A-frag (32KB)
    __shared__ __align__(16) unsigned short wpin[2][16384]; // g=12 of wh, wout (64KB)
    const int tid = threadIdx.x;
    const int w = tid >> 6, lane = tid & 63;
    const int col2 = lane & 15, kq = lane >> 4;
    const int bt = blockIdx.x;

    // per-thread column constants: biases + LDS frag write base (r=0)
    float b0v[4], b1v[4];
    int fb[4];
#pragma unroll
    for (int t = 0; t < 4; t++) {
        const int c = (w * 4 + t) * 16 + col2;
        b0v[t] = b0g[c];
        b1v[t] = b1g[c];
        fb[t] = ((w * 4 + t) >> 1) * 512 + (col2 & 7) + (((t * 2 + (col2 >> 3)) & 3) << 7) + kq * 32;
    }

    // wave's B-frag bases: tile ct=w*4+t, frag (ct,g) at ((ct*16+g)*64+lane) s16x8
    const s16x8* wlh = (const s16x8*)whp + (size_t)w * 4096 + lane;
    const s16x8* wlo = (const s16x8*)wop + (size_t)w * 4096 + lane;

    // ---- one-time staging: h tile -> sa[0]; g=12 -> wpin; g=13..15 -> VGPRs ----
    {
        const int4* src = (const int4*)(hf + (size_t)bt * 8192);
        int4* dst = (int4*)&sa[0][0];
        dst[tid] = src[tid];
        dst[tid + 512] = src[tid + 512];
    }
#pragma unroll
    for (int t = 0; t < 4; t++) {
        *(s16x8*)&wpin[0][((w * 4 + t) * 64 + lane) * 8] = wlh[t * 1024 + 12 * 64];
        *(s16x8*)&wpin[1][((w * 4 + t) * 64 + lane) * 8] = wlo[t * 1024 + 12 * 64];
    }
    s16x8 pnh13[4], pnh14[4], pnh15[4], pno13[4], pno14[4], pno15[4];
#pragma unroll
    for (int t = 0; t < 4; t++) {
        pnh13[t] = wlh[t * 1024 + 13 * 64];
        pnh14[t] = wlh[t * 1024 + 14 * 64];
        pnh15[t] = wlh[t * 1024 + 15 * 64];
        pno13[t] = wlo[t * 1024 + 13 * 64];
        pno14[t] = wlo[t * 1024 + 14 * 64];
        pno15[t] = wlo[t * 1024 + 15 * 64];
    }
    // L1-phase extras: x/xdot A-frags + wx B-frags (K=64: 2 groups)
    s16x8 xav[2], xdav[2], wxf[2][4];
#pragma unroll
    for (int g = 0; g < 2; g++) {
        xav[g] = *((const s16x8*)(xf + (size_t)bt * 1024 + g * 512) + lane);
        xdav[g] = *((const s16x8*)(xdf + (size_t)bt * 1024 + g * 512) + lane);
#pragma unroll
        for (int t = 0; t < 4; t++)
            wxf[g][t] = ((const s16x8*)wxp)[(size_t)((w * 4 + t) * 2 + g) * 64 + lane];
    }
    // preload L1's streamed g0/g1 (wh)
    s16x8 bfr0[4], bfr1[4];
#pragma unroll
    for (int t = 0; t < 4; t++) {
        bfr0[t] = wlh[t * 1024];
        bfr1[t] = wlh[t * 1024 + 64];
    }

    const unsigned short* A0 = &sa[0][lane * 8];
    const unsigned short* A1 = &sa[1][lane * 8];
    float dr[4][4], dt[4][4], hd[4][4];
    f32x4 acc[4], cac[4];

    __syncthreads();  // h + wpin staged

    // ---------------- Phase L1 (B=wh; tail prefetches wout g0/g1) ----------------
    CORE1(wlh, wlo, pnh13, pnh14, pnh15, 0, A0);
    {
        f32x4 vac[4] = {{0.f, 0.f, 0.f, 0.f}, {0.f, 0.f, 0.f, 0.f},
                        {0.f, 0.f, 0.f, 0.f}, {0.f, 0.f, 0.f, 0.f}};
#pragma unroll
        for (int g = 0; g < 2; g++)
#pragma unroll
            for (int t = 0; t < 4; t++) {
                acc[t] = MFMA16(xav[g], wxf[g][t], acc[t]);
                vac[t] = MFMA16(xdav[g], wxf[g][t], vac[t]);
            }
        __syncthreads();  // all waves done reading sa[0] (h)
#pragma unroll
        for (int t = 0; t < 4; t++)
#pragma unroll
            for (int r = 0; r < 4; r++) {
                const float l1 = acc[t][r] + b0v[t];
                const float dra = 1.f / (1.f + expf(-l1));
                dr[t][r] = dra;
                sa[0][fb[t] + r * 8] = f2bf(fmaxf(l1, 0.f));     // relu frag
                sa[1][fb[t] + r * 8] = f2bf(dra * vac[t][r]);    // s0 frag
            }
    }
    __syncthreads();  // relu/s0 visible

    // ---------------- Phase TH (B=wout, dual A; tail prefetches wh g0/g1) --------
    CORE2(wlo, wlh, pno13, pno14, pno15, 1, A0, A1);
    __syncthreads();  // all waves done reading sa[0]/sa[1]
#pragma unroll
    for (int t = 0; t < 4; t++)
#pragma unroll
        for (int r = 0; r < 4; r++) {
            const float th = tanhf(acc[t][r] + b1v[t]);
            const float dtv = 1.f - th * th;
            dt[t][r] = dtv;
            const float c0 = dtv * cac[t][r];
            hd[t][r] = c0;
            sa[0][fb[t] + r * 8] = f2bf(c0);  // curr0 frag (Neumann p=0 input)
        }
    __syncthreads();  // curr0 visible

    // ---------------- Neumann loop: 8 x (wh phase, wout phase) ----------------
    for (int it = 0; it < 8; it++) {
        // even phase: s = drelu*(curr@wh^T), read sa[0] -> write sa[1]
        CORE1(wlh, wlo, pnh13, pnh14, pnh15, 0, A0);
#pragma unroll
        for (int t = 0; t < 4; t++)
#pragma unroll
            for (int r = 0; r < 4; r++)
                sa[1][fb[t] + r * 8] = f2bf(dr[t][r] * acc[t][r]);
        __syncthreads();

        // odd phase: curr' = dtanh*(s@wout^T), read sa[1] -> write sa[0]
        CORE1(wlo, wlh, pno13, pno14, pno15, 1, A1);
        if (it < 7) {
#pragma unroll
            for (int t = 0; t < 4; t++)
#pragma unroll
                for (int r = 0; r < 4; r++) {
                    const float v = dt[t][r] * acc[t][r];
                    hd[t][r] += v;
                    sa[0][fb[t] + r * 8] = f2bf(v);
                }
            __syncthreads();
        } else {
#pragma unroll
            for (int t = 0; t < 4; t++)
#pragma unroll
                for (int r = 0; r < 4; r++) hd[t][r] += dt[t][r] * acc[t][r];
        }
    }

#pragma unroll
    for (int t = 0; t < 4; t++) {
        const int c = (w * 4 + t) * 16 + col2;
#pragma unroll
        for (int r = 0; r < 4; r++)
            outp[(size_t)(bt * 16 + kq * 4 + r) * HH + c] = hd[t][r];
    }
}

// ---------------------------------------------------------------------------
extern "C" void kernel_launch(void* const* d_in, const int* in_sizes, int n_in,
                              void* d_out, int out_size, void* d_ws, size_t ws_size,
                              hipStream_t stream) {
    const float* tg = (const float*)d_in[0];
    const float* h = (const float*)d_in[1];
    const float* coeffs = (const float*)d_in[2];
    const float* dcoeffs = (const float*)d_in[3];
    const float* tobs = (const float*)d_in[4];
    const float* wx = (const float*)d_in[5];
    const float* wh = (const float*)d_in[6];
    const float* wout = (const float*)d_in[7];
    const float* b0g = (const float*)d_in[8];
    const float* b1g = (const float*)d_in[9];
    float* outp = (float*)d_out;

    char* ws = (char*)d_ws;
    unsigned short* whp = (unsigned short*)(ws + 0);        // 512KB packed bf16
    unsigned short* wop = (unsigned short*)(ws + 524288);   // 512KB
    unsigned short* wxp = (unsigned short*)(ws + 1048576);  // 64KB
    unsigned short* hf  = (unsigned short*)(ws + 1114112);  // 256KB h A-frag
    unsigned short* xf  = (unsigned short*)(ws + 1376256);  // 32KB x A-frag
    unsigned short* xdf = (unsigned short*)(ws + 1409024);  // 32KB xdot A-frag

    k_pack<<<2752, 256, 0, stream>>>(wh, wout, wx, h, coeffs, dcoeffs, tobs, tg,
                                     whp, wop, wxp, hf, xf, xdf);
    k_fused<<<16, 512, 0, stream>>>(whp, wop, wxp, hf, xf, xdf, b0g, b1g, outp);
}

// Round 4
// 329.068 us; speedup vs baseline: 1.0266x; 1.0266x over previous
//
#include <hip/hip_runtime.h>

// Problem constants
#define BB 256   // batch
#define HH 512   // hidden
#define CC 64    // spline channels
#define NN 100   // time knots
#define KT 8     // K_TERMS

typedef short s16x8 __attribute__((ext_vector_type(8)));
typedef float f32x4 __attribute__((ext_vector_type(4)));

#define MFMA16(a, b, c) __builtin_amdgcn_mfma_f32_16x16x32_bf16((a), (b), (c), 0, 0, 0)

static __device__ __forceinline__ unsigned short f2bf(float f) {
    union { float f; unsigned int u; } v; v.f = f;
    unsigned int r = v.u + 0x7FFFu + ((v.u >> 16) & 1u);  // RNE
    return (unsigned short)(r >> 16);
}

// ---------------------------------------------------------------------------
// A-frag layout for a 16-row x 512-col bf16 activation tile t (8192 halfwords):
//   F[t*8192 + g*512 + lane*8 + e] = M[lane&15][g*32 + (lane>>4)*8 + e]
// MFMA A-operand for Ktile g is a coalesced 16B/lane load at lane*8.
// ---------------------------------------------------------------------------

// ---------------------------------------------------------------------------
// k_pack: weight bf16 conversion into MFMA-frag-packed layout + h conversion +
// cubic spline evaluation (x, xdot).  (Round-1 proven version, counters removed.)
// ---------------------------------------------------------------------------
__global__ void k_pack(const float* __restrict__ wh, const float* __restrict__ wout,
                       const float* __restrict__ wx, const float* __restrict__ h,
                       const float* __restrict__ coeffs, const float* __restrict__ dcoeffs,
                       const float* __restrict__ tobs, const float* __restrict__ tg,
                       unsigned short* __restrict__ whp, unsigned short* __restrict__ wop,
                       unsigned short* __restrict__ wxp, unsigned short* __restrict__ hb,
                       unsigned short* __restrict__ xb, unsigned short* __restrict__ xdb) {
    int gid = blockIdx.x * 256 + threadIdx.x;
    if (gid < 524288) {                       // wh / wout packed (262144 each)
        const float* src = (gid < 262144) ? wh : wout;
        unsigned short* dst = (gid < 262144) ? whp : wop;
        int p = gid & 262143;
        int e = p & 7, lane = (p >> 3) & 63, g = (p >> 9) & 15, cg = (p >> 13) & 1, w = p >> 14;
        int row = w * 32 + cg * 16 + (lane & 15);
        int k = g * 32 + (lane >> 4) * 8 + e;
        dst[p] = f2bf(src[row * HH + k]);
    } else if (gid < 557056) {                // wx packed (32768)
        int p = gid - 524288;
        int e = p & 7, lane = (p >> 3) & 63, g = (p >> 9) & 1, cg = (p >> 10) & 1, w = p >> 11;
        int row = w * 32 + cg * 16 + (lane & 15);
        int k = g * 32 + (lane >> 4) * 8 + e;
        wxp[p] = f2bf(wx[row * CC + k]);
    } else if (gid < 688128) {                // h -> bf16 row-major (131072)
        int p = gid - 557056;
        hb[p] = f2bf(h[p]);
    } else if (gid < 704512) {                // spline eval: x, xdot (16384)
        int p = gid - 688128;
        int b = p >> 6, c = p & 63;
        float t = tg[0];
        int cntv = 0;
        for (int n = 0; n < NN; n++) cntv += (tobs[n] <= t) ? 1 : 0;
        int idx = cntv - 1;
        idx = idx < 0 ? 0 : (idx > NN - 2 ? NN - 2 : idx);  // clip to [0, 98]
        float dt = t - tobs[idx];
        const float* cb = coeffs + ((size_t)(b * (NN - 1) + idx) * 4) * CC + c;
        float xv = cb[0] + dt * (cb[CC] + dt * (cb[2 * CC] + dt * cb[3 * CC]));
        const float* db = dcoeffs + ((size_t)(b * (NN - 1) + idx) * 4) * CC + c;
        float xd = db[0] + dt * (db[CC] + dt * (db[2 * CC] + dt * db[3 * CC]));
        xb[p] = f2bf(xv);
        xdb[p] = f2bf(xd);
    }
}

// ---------------------------------------------------------------------------
// k_l1: l1 = x@wx^T + h@wh^T + b0 -> relu(bf16), drelu=sigmoid(l1) (f32)
//       fused: v = xdot@wx^T ; s0 = drelu*v (bf16)          (round-1 proven)
// ---------------------------------------------------------------------------
__global__ void k_l1(const unsigned short* __restrict__ whp, const unsigned short* __restrict__ wxp,
                     const unsigned short* __restrict__ hb, const unsigned short* __restrict__ xb,
                     const unsigned short* __restrict__ xdb, const float* __restrict__ b0g,
                     unsigned short* __restrict__ relu_b, float* __restrict__ drelu_f,
                     unsigned short* __restrict__ s0_b) {
    __shared__ unsigned short sh[32][520];
    __shared__ unsigned short sx[32][72];
    __shared__ unsigned short sxd[32][72];
    int tid = threadIdx.x;
    int b0 = blockIdx.x * 32;
    int it = blockIdx.y;
    for (int idx = tid; idx < 32 * 64; idx += 256) {
        int r = idx >> 6, c8 = idx & 63;
        *(int4*)&sh[r][c8 * 8] = *(const int4*)&hb[(b0 + r) * HH + c8 * 8];
    }
    for (int idx = tid; idx < 32 * 8; idx += 256) {
        int r = idx >> 3, c8 = idx & 7;
        *(int4*)&sx[r][c8 * 8] = *(const int4*)&xb[(b0 + r) * CC + c8 * 8];
        *(int4*)&sxd[r][c8 * 8] = *(const int4*)&xdb[(b0 + r) * CC + c8 * 8];
    }
    __syncthreads();
    int wv = tid >> 6, lane = tid & 63, col = lane & 15, kq = lane >> 4;
    int isub = it * 64 + wv * 16;
    int wpk = isub >> 5, cg = (isub >> 4) & 1;
    f32x4 acc0 = {0.f, 0.f, 0.f, 0.f}, acc1 = {0.f, 0.f, 0.f, 0.f};
    f32x4 vac0 = {0.f, 0.f, 0.f, 0.f}, vac1 = {0.f, 0.f, 0.f, 0.f};
    const s16x8* whfrag = (const s16x8*)whp + (size_t)((wpk * 2 + cg) * 16) * 64 + lane;
#pragma unroll
    for (int g = 0; g < 16; g++) {
        s16x8 bf = whfrag[g * 64];
        s16x8 a0 = *(const s16x8*)&sh[col][g * 32 + kq * 8];
        s16x8 a1 = *(const s16x8*)&sh[16 + col][g * 32 + kq * 8];
        acc0 = MFMA16(a0, bf, acc0);
        acc1 = MFMA16(a1, bf, acc1);
    }
    const s16x8* wxfrag = (const s16x8*)wxp + (size_t)((wpk * 2 + cg) * 2) * 64 + lane;
#pragma unroll
    for (int g = 0; g < 2; g++) {
        s16x8 bf = wxfrag[g * 64];
        s16x8 a0 = *(const s16x8*)&sx[col][g * 32 + kq * 8];
        s16x8 a1 = *(const s16x8*)&sx[16 + col][g * 32 + kq * 8];
        acc0 = MFMA16(a0, bf, acc0);
        acc1 = MFMA16(a1, bf, acc1);
        s16x8 d0 = *(const s16x8*)&sxd[col][g * 32 + kq * 8];
        s16x8 d1 = *(const s16x8*)&sxd[16 + col][g * 32 + kq * 8];
        vac0 = MFMA16(d0, bf, vac0);
        vac1 = MFMA16(d1, bf, vac1);
    }
    int ic = isub + col;
    float bias = b0g[ic];
#pragma unroll
    for (int r = 0; r < 4; r++) {
        int bb = b0 + kq * 4 + r;
        float l1a = acc0[r] + bias;
        float dra = 1.f / (1.f + expf(-l1a));
        relu_b[bb * HH + ic] = f2bf(fmaxf(l1a, 0.f));
        drelu_f[bb * HH + ic] = dra;
        s0_b[bb * HH + ic] = f2bf(dra * vac0[r]);
        float l1b = acc1[r] + bias;
        float drb = 1.f / (1.f + expf(-l1b));
        relu_b[(bb + 16) * HH + ic] = f2bf(fmaxf(l1b, 0.f));
        drelu_f[(bb + 16) * HH + ic] = drb;
        s0_b[(bb + 16) * HH + ic] = f2bf(drb * vac1[r]);
    }
}

// ---------------------------------------------------------------------------
// k_th: z = relu@wout^T + b1 -> th=tanh(z), dtanh=1-th^2 (f32)
//       fused: curr0 = dtanh * (s0@wout^T); stores curr0 f32 row-major and
//       bf16 A-frag (loop kernel phase-0 input).          (round-1 proven)
// ---------------------------------------------------------------------------
__global__ void k_th(const unsigned short* __restrict__ wop, const unsigned short* __restrict__ relu_b,
                     const unsigned short* __restrict__ s0_b, const float* __restrict__ b1g,
                     float* __restrict__ dtanh_f, unsigned short* __restrict__ curr_b,
                     float* __restrict__ curr0_f) {
    __shared__ unsigned short sr[32][520];
    __shared__ unsigned short ss0[32][520];
    int tid = threadIdx.x;
    int b0 = blockIdx.x * 32;
    int it = blockIdx.y;
    for (int idx = tid; idx < 32 * 64; idx += 256) {
        int r = idx >> 6, c8 = idx & 63;
        *(int4*)&sr[r][c8 * 8] = *(const int4*)&relu_b[(b0 + r) * HH + c8 * 8];
        *(int4*)&ss0[r][c8 * 8] = *(const int4*)&s0_b[(b0 + r) * HH + c8 * 8];
    }
    __syncthreads();
    int wv = tid >> 6, lane = tid & 63, col = lane & 15, kq = lane >> 4;
    int isub = it * 64 + wv * 16;
    int wpk = isub >> 5, cg = (isub >> 4) & 1;
    f32x4 acc0 = {0.f, 0.f, 0.f, 0.f}, acc1 = {0.f, 0.f, 0.f, 0.f};
    f32x4 cac0 = {0.f, 0.f, 0.f, 0.f}, cac1 = {0.f, 0.f, 0.f, 0.f};
    const s16x8* wofrag = (const s16x8*)wop + (size_t)((wpk * 2 + cg) * 16) * 64 + lane;
#pragma unroll
    for (int g = 0; g < 16; g++) {
        s16x8 bf = wofrag[g * 64];
        s16x8 a0 = *(const s16x8*)&sr[col][g * 32 + kq * 8];
        s16x8 a1 = *(const s16x8*)&sr[16 + col][g * 32 + kq * 8];
        acc0 = MFMA16(a0, bf, acc0);
        acc1 = MFMA16(a1, bf, acc1);
        s16x8 p0 = *(const s16x8*)&ss0[col][g * 32 + kq * 8];
        s16x8 p1 = *(const s16x8*)&ss0[16 + col][g * 32 + kq * 8];
        cac0 = MFMA16(p0, bf, cac0);
        cac1 = MFMA16(p1, bf, cac1);
    }
    int ic = isub + col;
    float bias = b1g[ic];
    int fc = (ic >> 5) * 512 + (ic & 7) + (((ic >> 3) & 3) << 7);
#pragma unroll
    for (int r = 0; r < 4; r++) {
        int bb = b0 + kq * 4 + r;
        int row8 = (kq * 4 + r) * 8;
        float th_a = tanhf(acc0[r] + bias);
        float dta = 1.f - th_a * th_a;
        float c0a = dta * cac0[r];
        dtanh_f[bb * HH + ic] = dta;
        curr_b[(bb >> 4) * 8192 + fc + row8] = f2bf(c0a);
        curr0_f[bb * HH + ic] = c0a;
        float th_b = tanhf(acc1[r] + bias);
        float dtb = 1.f - th_b * th_b;
        float c0b = dtb * cac1[r];
        dtanh_f[(bb + 16) * HH + ic] = dtb;
        curr_b[((bb + 16) >> 4) * 8192 + fc + row8] = f2bf(c0b);
        curr0_f[(bb + 16) * HH + ic] = c0b;
    }
}

// ---------------------------------------------------------------------------
// k_loop4: Neumann loop, 16 blocks x 1024 threads (16 waves/CU, 2 col-tiles
// per wave). Changes vs round-1 k_loop3 (71us):
//  - 16 waves (was 8): 2x more loads in flight -> closer to the ~60 B/cy
//    per-CU L2 link (round-1 measured ~43 B/cy).
//  - LDS-pin K-group g=15 of wh AND wout (64KB; total LDS 96KB): stream
//    480KB/phase instead of 512KB. No VGPR pinning (round-3 spill lesson).
//  - tail-prefetch: the last two dbuf refills fetch the NEXT phase's g0/g1,
//    so the vmcnt(0) drain at the barrier completes them for free. Buffer
//    parity alternates per phase (XORc compile-time constant).
// ---------------------------------------------------------------------------
#define PHASE(WL, WLN, PIN, XORc, AR) do {                                     \
    _Pragma("unroll") for (int t = 0; t < 2; t++) acc[t] = (f32x4){0.f,0.f,0.f,0.f}; \
    {                                                                          \
        const s16x8 a15 = *(const s16x8*)((AR) + 15 * 512);                    \
        _Pragma("unroll") for (int t = 0; t < 2; t++)                          \
            acc[t] = MFMA16(a15, (PIN)[t * 64], acc[t]);                       \
    }                                                                          \
    _Pragma("unroll")                                                          \
    for (int g = 0; g < 15; g++) {                                             \
        const s16x8 a = *(const s16x8*)((AR) + g * 512);                       \
        const int bi = (g & 1) ^ (XORc);                                       \
        _Pragma("unroll") for (int t = 0; t < 2; t++)                          \
            acc[t] = MFMA16(a, bfr[bi][t], acc[t]);                            \
        const s16x8* ws = (g < 13) ? (WL) : (WLN);                             \
        const int gg = (g < 13) ? (g + 2) : (g - 13);                          \
        _Pragma("unroll") for (int t = 0; t < 2; t++)                          \
            bfr[bi][t] = ws[t * 1024 + gg * 64];                               \
    }                                                                          \
} while (0)

__global__ __launch_bounds__(1024, 4) void k_loop4(
    const unsigned short* __restrict__ whp, const unsigned short* __restrict__ wop,
    const unsigned short* __restrict__ curr_b, const float* __restrict__ curr0_f,
    const float* __restrict__ drelu_f, const float* __restrict__ dtanh_f,
    float* __restrict__ outp) {
    __shared__ __align__(16) unsigned short sa[2][8192];   // ping-pong A-frag (32KB)
    __shared__ __align__(16) unsigned short wpinh[16384];  // wh  g=15 (32KB)
    __shared__ __align__(16) unsigned short wpino[16384];  // wout g=15 (32KB)
    const int tid = threadIdx.x;
    const int w = tid >> 6, lane = tid & 63;
    const int col2 = lane & 15, kq = lane >> 4;
    const int bt = blockIdx.x;

    // stage curr0 tile (A-frag from k_th) into sa[0]: 1024 int4
    {
        const int4* src = (const int4*)(curr_b + (size_t)bt * 8192);
        ((int4*)&sa[0][0])[tid] = src[tid];
    }
    // stage pinned g=15 of wh/wout: dest (ct*64+lane) int4, src frag (ct,15)
    {
        const int4* s0 = (const int4*)whp;
        const int4* s1 = (const int4*)wop;
        int4* d0 = (int4*)wpinh;
        int4* d1 = (int4*)wpino;
        for (int i = tid; i < 2048; i += 1024) {
            const int srcIdx = (i >> 6) * 1024 + 15 * 64 + (i & 63);
            d0[i] = s0[srcIdx];
            d1[i] = s1[srcIdx];
        }
    }

    // per-thread diagonals + h_dot accumulator: 2 col-tiles x 4 rows
    float dr[2][4], dt[2][4], hd[2][4];
#pragma unroll
    for (int t = 0; t < 2; t++) {
        const int c = (w * 2 + t) * 16 + col2;
#pragma unroll
        for (int r = 0; r < 4; r++) {
            const int row = bt * 16 + kq * 4 + r;
            dr[t][r] = drelu_f[row * HH + c];
            dt[t][r] = dtanh_f[row * HH + c];
            hd[t][r] = curr0_f[row * HH + c];
        }
    }
    // LDS frag write base (r=0) for col c=ct*16+col2:
    //   pos(m,k) = (k>>5)*512 + (k&7) + (((k>>3)&3)<<7) + m*8, m=kq*4+r
    int fb[2];
#pragma unroll
    for (int t = 0; t < 2; t++) {
        const int ct = w * 2 + t;
        fb[t] = (ct >> 1) * 512 + (col2 & 7) + ((((ct & 1) * 2 + (col2 >> 3)) & 3) << 7) + kq * 32;
    }

    const s16x8* wlh = (const s16x8*)whp + (size_t)(w * 2) * 1024 + lane;
    const s16x8* wlo = (const s16x8*)wop + (size_t)(w * 2) * 1024 + lane;
    const unsigned short* A0 = &sa[0][lane * 8];
    const unsigned short* A1 = &sa[1][lane * 8];
    const s16x8* pinh = (const s16x8*)&wpinh[0] + (size_t)(w * 2) * 64 + lane;
    const s16x8* pino = (const s16x8*)&wpino[0] + (size_t)(w * 2) * 64 + lane;

    f32x4 acc[2];
    s16x8 bfr[2][2];
    // prologue: wh g0 -> bfr[0], g1 -> bfr[1]
#pragma unroll
    for (int t = 0; t < 2; t++) {
        bfr[0][t] = wlh[t * 1024 + 0 * 64];
        bfr[1][t] = wlh[t * 1024 + 1 * 64];
    }

    __syncthreads();  // curr0 + pinned weights staged

    for (int it = 0; it < 8; it++) {
        // even phase: s = drelu*(curr@wh^T), read sa[0] -> write sa[1]
        PHASE(wlh, wlo, pinh, 0, A0);
#pragma unroll
        for (int t = 0; t < 2; t++)
#pragma unroll
            for (int r = 0; r < 4; r++)
                sa[1][fb[t] + r * 8] = f2bf(dr[t][r] * acc[t][r]);
        __syncthreads();

        // odd phase: curr' = dtanh*(s@wout^T), read sa[1] -> write sa[0]
        PHASE(wlo, wlh, pino, 1, A1);
        if (it < 7) {
#pragma unroll
            for (int t = 0; t < 2; t++)
#pragma unroll
                for (int r = 0; r < 4; r++) {
                    const float v = dt[t][r] * acc[t][r];
                    hd[t][r] += v;
                    sa[0][fb[t] + r * 8] = f2bf(v);
                }
            __syncthreads();
        } else {
#pragma unroll
            for (int t = 0; t < 2; t++)
#pragma unroll
                for (int r = 0; r < 4; r++) hd[t][r] += dt[t][r] * acc[t][r];
        }
    }

#pragma unroll
    for (int t = 0; t < 2; t++) {
        const int c = (w * 2 + t) * 16 + col2;
#pragma unroll
        for (int r = 0; r < 4; r++)
            outp[(size_t)(bt * 16 + kq * 4 + r) * HH + c] = hd[t][r];
    }
}

// ---------------------------------------------------------------------------
extern "C" void kernel_launch(void* const* d_in, const int* in_sizes, int n_in,
                              void* d_out, int out_size, void* d_ws, size_t ws_size,
                              hipStream_t stream) {
    const float* tg = (const float*)d_in[0];
    const float* h = (const float*)d_in[1];
    const float* coeffs = (const float*)d_in[2];
    const float* dcoeffs = (const float*)d_in[3];
    const float* tobs = (const float*)d_in[4];
    const float* wx = (const float*)d_in[5];
    const float* wh = (const float*)d_in[6];
    const float* wout = (const float*)d_in[7];
    const float* b0g = (const float*)d_in[8];
    const float* b1g = (const float*)d_in[9];
    float* outp = (float*)d_out;

    char* ws = (char*)d_ws;
    unsigned short* whp    = (unsigned short*)(ws + 0);        // 512KB packed bf16
    unsigned short* wop    = (unsigned short*)(ws + 524288);   // 512KB
    unsigned short* wxp    = (unsigned short*)(ws + 1048576);  // 64KB
    unsigned short* hb     = (unsigned short*)(ws + 1114112);  // 256KB
    unsigned short* xb     = (unsigned short*)(ws + 1376256);  // 32KB
    unsigned short* xdb    = (unsigned short*)(ws + 1409024);  // 32KB
    unsigned short* relu_b = (unsigned short*)(ws + 1441792);  // 256KB
    unsigned short* s0_b   = (unsigned short*)(ws + 1703936);  // 256KB
    float* drelu_f         = (float*)(ws + 1966080);           // 512KB
    float* dtanh_f         = (float*)(ws + 2490368);           // 512KB
    unsigned short* curr_b = (unsigned short*)(ws + 3014656);  // 256KB (A-frag)
    float* curr0_f         = (float*)(ws + 3276800);           // 512KB

    k_pack<<<2752, 256, 0, stream>>>(wh, wout, wx, h, coeffs, dcoeffs, tobs, tg,
                                     whp, wop, wxp, hb, xb, xdb);
    k_l1<<<dim3(8, 8), 256, 0, stream>>>(whp, wxp, hb, xb, xdb, b0g, relu_b, drelu_f, s0_b);
    k_th<<<dim3(8, 8), 256, 0, stream>>>(wop, relu_b, s0_b, b1g, dtanh_f, curr_b, curr0_f);
    k_loop4<<<16, 1024, 0, stream>>>(whp, wop, curr_b, curr0_f, drelu_f, dtanh_f, outp);
}

// Round 5
// 181.804 us; speedup vs baseline: 1.8582x; 1.8100x over previous
//
#include <hip/hip_runtime.h>

// Problem constants
#define BB 256   // batch
#define HH 512   // hidden
#define CC 64    // spline channels
#define NN 100   // time knots
#define KT 8     // K_TERMS

typedef short s16x8 __attribute__((ext_vector_type(8)));
typedef float f32x4 __attribute__((ext_vector_type(4)));

#define MFMA16(a, b, c) __builtin_amdgcn_mfma_f32_16x16x32_bf16((a), (b), (c), 0, 0, 0)

static __device__ __forceinline__ unsigned short f2bf(float f) {
    union { float f; unsigned int u; } v; v.f = f;
    unsigned int r = v.u + 0x7FFFu + ((v.u >> 16) & 1u);  // RNE
    return (unsigned short)(r >> 16);
}

// ---------------------------------------------------------------------------
// A-frag layout for a 16-row x 512-col bf16 activation tile t (8192 halfwords):
//   F[t*8192 + g*512 + lane*8 + e] = M[lane&15][g*32 + (lane>>4)*8 + e]
// MFMA A-operand for Ktile g is a coalesced 16B/lane load at lane*8.
// ---------------------------------------------------------------------------

// ---------------------------------------------------------------------------
// k_pack: weight bf16 conversion into MFMA-frag-packed layout + h conversion +
// cubic spline evaluation (x, xdot).  (Round-1 proven version.)
// ---------------------------------------------------------------------------
__global__ void k_pack(const float* __restrict__ wh, const float* __restrict__ wout,
                       const float* __restrict__ wx, const float* __restrict__ h,
                       const float* __restrict__ coeffs, const float* __restrict__ dcoeffs,
                       const float* __restrict__ tobs, const float* __restrict__ tg,
                       unsigned short* __restrict__ whp, unsigned short* __restrict__ wop,
                       unsigned short* __restrict__ wxp, unsigned short* __restrict__ hb,
                       unsigned short* __restrict__ xb, unsigned short* __restrict__ xdb) {
    int gid = blockIdx.x * 256 + threadIdx.x;
    if (gid < 524288) {                       // wh / wout packed (262144 each)
        const float* src = (gid < 262144) ? wh : wout;
        unsigned short* dst = (gid < 262144) ? whp : wop;
        int p = gid & 262143;
        int e = p & 7, lane = (p >> 3) & 63, g = (p >> 9) & 15, cg = (p >> 13) & 1, w = p >> 14;
        int row = w * 32 + cg * 16 + (lane & 15);
        int k = g * 32 + (lane >> 4) * 8 + e;
        dst[p] = f2bf(src[row * HH + k]);
    } else if (gid < 557056) {                // wx packed (32768)
        int p = gid - 524288;
        int e = p & 7, lane = (p >> 3) & 63, g = (p >> 9) & 1, cg = (p >> 10) & 1, w = p >> 11;
        int row = w * 32 + cg * 16 + (lane & 15);
        int k = g * 32 + (lane >> 4) * 8 + e;
        wxp[p] = f2bf(wx[row * CC + k]);
    } else if (gid < 688128) {                // h -> bf16 row-major (131072)
        int p = gid - 557056;
        hb[p] = f2bf(h[p]);
    } else if (gid < 704512) {                // spline eval: x, xdot (16384)
        int p = gid - 688128;
        int b = p >> 6, c = p & 63;
        float t = tg[0];
        int cntv = 0;
        for (int n = 0; n < NN; n++) cntv += (tobs[n] <= t) ? 1 : 0;
        int idx = cntv - 1;
        idx = idx < 0 ? 0 : (idx > NN - 2 ? NN - 2 : idx);  // clip to [0, 98]
        float dt = t - tobs[idx];
        const float* cb = coeffs + ((size_t)(b * (NN - 1) + idx) * 4) * CC + c;
        float xv = cb[0] + dt * (cb[CC] + dt * (cb[2 * CC] + dt * cb[3 * CC]));
        const float* db = dcoeffs + ((size_t)(b * (NN - 1) + idx) * 4) * CC + c;
        float xd = db[0] + dt * (db[CC] + dt * (db[2 * CC] + dt * db[3 * CC]));
        xb[p] = f2bf(xv);
        xdb[p] = f2bf(xd);
    }
}

// ---------------------------------------------------------------------------
// k_l1: l1 = x@wx^T + h@wh^T + b0 -> relu(bf16), drelu=sigmoid(l1) (f32)
//       fused: v = xdot@wx^T ; s0 = drelu*v (bf16)          (round-1 proven)
// ---------------------------------------------------------------------------
__global__ void k_l1(const unsigned short* __restrict__ whp, const unsigned short* __restrict__ wxp,
                     const unsigned short* __restrict__ hb, const unsigned short* __restrict__ xb,
                     const unsigned short* __restrict__ xdb, const float* __restrict__ b0g,
                     unsigned short* __restrict__ relu_b, float* __restrict__ drelu_f,
                     unsigned short* __restrict__ s0_b) {
    __shared__ unsigned short sh[32][520];
    __shared__ unsigned short sx[32][72];
    __shared__ unsigned short sxd[32][72];
    int tid = threadIdx.x;
    int b0 = blockIdx.x * 32;
    int it = blockIdx.y;
    for (int idx = tid; idx < 32 * 64; idx += 256) {
        int r = idx >> 6, c8 = idx & 63;
        *(int4*)&sh[r][c8 * 8] = *(const int4*)&hb[(b0 + r) * HH + c8 * 8];
    }
    for (int idx = tid; idx < 32 * 8; idx += 256) {
        int r = idx >> 3, c8 = idx & 7;
        *(int4*)&sx[r][c8 * 8] = *(const int4*)&xb[(b0 + r) * CC + c8 * 8];
        *(int4*)&sxd[r][c8 * 8] = *(const int4*)&xdb[(b0 + r) * CC + c8 * 8];
    }
    __syncthreads();
    int wv = tid >> 6, lane = tid & 63, col = lane & 15, kq = lane >> 4;
    int isub = it * 64 + wv * 16;
    int wpk = isub >> 5, cg = (isub >> 4) & 1;
    f32x4 acc0 = {0.f, 0.f, 0.f, 0.f}, acc1 = {0.f, 0.f, 0.f, 0.f};
    f32x4 vac0 = {0.f, 0.f, 0.f, 0.f}, vac1 = {0.f, 0.f, 0.f, 0.f};
    const s16x8* whfrag = (const s16x8*)whp + (size_t)((wpk * 2 + cg) * 16) * 64 + lane;
#pragma unroll
    for (int g = 0; g < 16; g++) {
        s16x8 bf = whfrag[g * 64];
        s16x8 a0 = *(const s16x8*)&sh[col][g * 32 + kq * 8];
        s16x8 a1 = *(const s16x8*)&sh[16 + col][g * 32 + kq * 8];
        acc0 = MFMA16(a0, bf, acc0);
        acc1 = MFMA16(a1, bf, acc1);
    }
    const s16x8* wxfrag = (const s16x8*)wxp + (size_t)((wpk * 2 + cg) * 2) * 64 + lane;
#pragma unroll
    for (int g = 0; g < 2; g++) {
        s16x8 bf = wxfrag[g * 64];
        s16x8 a0 = *(const s16x8*)&sx[col][g * 32 + kq * 8];
        s16x8 a1 = *(const s16x8*)&sx[16 + col][g * 32 + kq * 8];
        acc0 = MFMA16(a0, bf, acc0);
        acc1 = MFMA16(a1, bf, acc1);
        s16x8 d0 = *(const s16x8*)&sxd[col][g * 32 + kq * 8];
        s16x8 d1 = *(const s16x8*)&sxd[16 + col][g * 32 + kq * 8];
        vac0 = MFMA16(d0, bf, vac0);
        vac1 = MFMA16(d1, bf, vac1);
    }
    int ic = isub + col;
    float bias = b0g[ic];
#pragma unroll
    for (int r = 0; r < 4; r++) {
        int bb = b0 + kq * 4 + r;
        float l1a = acc0[r] + bias;
        float dra = 1.f / (1.f + expf(-l1a));
        relu_b[bb * HH + ic] = f2bf(fmaxf(l1a, 0.f));
        drelu_f[bb * HH + ic] = dra;
        s0_b[bb * HH + ic] = f2bf(dra * vac0[r]);
        float l1b = acc1[r] + bias;
        float drb = 1.f / (1.f + expf(-l1b));
        relu_b[(bb + 16) * HH + ic] = f2bf(fmaxf(l1b, 0.f));
        drelu_f[(bb + 16) * HH + ic] = drb;
        s0_b[(bb + 16) * HH + ic] = f2bf(drb * vac1[r]);
    }
}

// ---------------------------------------------------------------------------
// k_th: z = relu@wout^T + b1 -> th=tanh(z), dtanh=1-th^2 (f32)
//       fused: curr0 = dtanh * (s0@wout^T); stores curr0 f32 row-major and
//       bf16 A-frag (loop kernel phase-0 input).          (round-1 proven)
// ---------------------------------------------------------------------------
__global__ void k_th(const unsigned short* __restrict__ wop, const unsigned short* __restrict__ relu_b,
                     const unsigned short* __restrict__ s0_b, const float* __restrict__ b1g,
                     float* __restrict__ dtanh_f, unsigned short* __restrict__ curr_b,
                     float* __restrict__ curr0_f) {
    __shared__ unsigned short sr[32][520];
    __shared__ unsigned short ss0[32][520];
    int tid = threadIdx.x;
    int b0 = blockIdx.x * 32;
    int it = blockIdx.y;
    for (int idx = tid; idx < 32 * 64; idx += 256) {
        int r = idx >> 6, c8 = idx & 63;
        *(int4*)&sr[r][c8 * 8] = *(const int4*)&relu_b[(b0 + r) * HH + c8 * 8];
        *(int4*)&ss0[r][c8 * 8] = *(const int4*)&s0_b[(b0 + r) * HH + c8 * 8];
    }
    __syncthreads();
    int wv = tid >> 6, lane = tid & 63, col = lane & 15, kq = lane >> 4;
    int isub = it * 64 + wv * 16;
    int wpk = isub >> 5, cg = (isub >> 4) & 1;
    f32x4 acc0 = {0.f, 0.f, 0.f, 0.f}, acc1 = {0.f, 0.f, 0.f, 0.f};
    f32x4 cac0 = {0.f, 0.f, 0.f, 0.f}, cac1 = {0.f, 0.f, 0.f, 0.f};
    const s16x8* wofrag = (const s16x8*)wop + (size_t)((wpk * 2 + cg) * 16) * 64 + lane;
#pragma unroll
    for (int g = 0; g < 16; g++) {
        s16x8 bf = wofrag[g * 64];
        s16x8 a0 = *(const s16x8*)&sr[col][g * 32 + kq * 8];
        s16x8 a1 = *(const s16x8*)&sr[16 + col][g * 32 + kq * 8];
        acc0 = MFMA16(a0, bf, acc0);
        acc1 = MFMA16(a1, bf, acc1);
        s16x8 p0 = *(const s16x8*)&ss0[col][g * 32 + kq * 8];
        s16x8 p1 = *(const s16x8*)&ss0[16 + col][g * 32 + kq * 8];
        cac0 = MFMA16(p0, bf, cac0);
        cac1 = MFMA16(p1, bf, cac1);
    }
    int ic = isub + col;
    float bias = b1g[ic];
    int fc = (ic >> 5) * 512 + (ic & 7) + (((ic >> 3) & 3) << 7);
#pragma unroll
    for (int r = 0; r < 4; r++) {
        int bb = b0 + kq * 4 + r;
        int row8 = (kq * 4 + r) * 8;
        float th_a = tanhf(acc0[r] + bias);
        float dta = 1.f - th_a * th_a;
        float c0a = dta * cac0[r];
        dtanh_f[bb * HH + ic] = dta;
        curr_b[(bb >> 4) * 8192 + fc + row8] = f2bf(c0a);
        curr0_f[bb * HH + ic] = c0a;
        float th_b = tanhf(acc1[r] + bias);
        float dtb = 1.f - th_b * th_b;
        float c0b = dtb * cac1[r];
        dtanh_f[(bb + 16) * HH + ic] = dtb;
        curr_b[((bb + 16) >> 4) * 8192 + fc + row8] = f2bf(c0b);
        curr0_f[(bb + 16) * HH + ic] = c0b;
    }
}

// ---------------------------------------------------------------------------
// k_loop5: Neumann loop — round-1 k_loop3 structure EXACTLY, with the single
// change 8 waves -> 16 waves (1024 threads, 2 col-tiles/wave instead of 4).
// Theory: round-1 ran the per-CU weight stream at ~44 B/cy vs the ~56 B/cy
// L2 link; 2x waves doubles loads-in-flight. No LDS pinning, no tail
// prefetch, no launch_bounds min-waves (rounds 3/4 scratch-spill lessons).
// ---------------------------------------------------------------------------
__global__ __launch_bounds__(1024) void k_loop5(
    const unsigned short* __restrict__ whp, const unsigned short* __restrict__ wop,
    const unsigned short* __restrict__ curr_b, const float* __restrict__ curr0_f,
    const float* __restrict__ drelu_f, const float* __restrict__ dtanh_f,
    float* __restrict__ outp) {
    __shared__ __align__(16) unsigned short sa[2][8192];  // ping-pong A-frag (16KB each)
    const int tid = threadIdx.x;
    const int w = tid >> 6, lane = tid & 63;
    const int col2 = lane & 15, kq = lane >> 4;
    const int bt = blockIdx.x;

    // stage curr0 tile (already A-frag layout from k_th) into sa[0]: 1024 int4
    {
        const int4* src = (const int4*)(curr_b + (size_t)bt * 8192);
        ((int4*)&sa[0][0])[tid] = src[tid];
    }

    // per-thread diagonals + h_dot accumulator: 2 col-tiles x 4 rows
    float dr[2][4], dt[2][4], hd[2][4];
#pragma unroll
    for (int t = 0; t < 2; t++) {
        const int c = (w * 2 + t) * 16 + col2;
#pragma unroll
        for (int r = 0; r < 4; r++) {
            const int row = bt * 16 + kq * 4 + r;
            dr[t][r] = drelu_f[row * HH + c];
            dt[t][r] = dtanh_f[row * HH + c];
            hd[t][r] = curr0_f[row * HH + c];
        }
    }

    // LDS halfword index (r=0) for (row m=kq*4+r, col c=ct*16+col2), ct=w*2+t:
    //   pos(m,k) = (k>>5)*512 + (k&7) + (((k>>3)&3)<<7) + m*8
    int fb[2];
#pragma unroll
    for (int t = 0; t < 2; t++)
        fb[t] = w * 512 + (col2 & 7) + (((t * 2 + (col2 >> 3)) & 3) << 7) + kq * 32;

    // wave's B-frag base: tiles ct = w*2+t; frag (ct,g) at ((ct*16+g)*64+lane) s16x8
    const s16x8* wlh = (const s16x8*)whp + (size_t)w * 2048 + lane;
    const s16x8* wlo = (const s16x8*)wop + (size_t)w * 2048 + lane;
    const unsigned short* A0 = &sa[0][lane * 8];
    const unsigned short* A1 = &sa[1][lane * 8];

    __syncthreads();  // curr0 staged

    for (int p = 0; p < 16; p++) {
        const s16x8* wl = (p & 1) ? wlo : wlh;          // even: wh, odd: wout
        const unsigned short* Ar = (p & 1) ? A1 : A0;   // read sa[p&1]
        f32x4 acc[2] = {{0.f, 0.f, 0.f, 0.f}, {0.f, 0.f, 0.f, 0.f}};
        s16x8 bfr[2][2];
#pragma unroll
        for (int t = 0; t < 2; t++) bfr[0][t] = wl[t * 1024];
#pragma unroll
        for (int g = 0; g < 16; g++) {
            if (g < 15) {
#pragma unroll
                for (int t = 0; t < 2; t++) bfr[(g + 1) & 1][t] = wl[t * 1024 + (g + 1) * 64];
            }
            const s16x8 a = *(const s16x8*)(Ar + (size_t)g * 512);
#pragma unroll
            for (int t = 0; t < 2; t++) acc[t] = MFMA16(a, bfr[g & 1][t], acc[t]);
        }
        unsigned short* Aw = &sa[(p + 1) & 1][0];       // write the other buffer
        if (p & 1) {            // wout phase: curr' = dtanh*(s@wout^T); h_dot += curr'
            if (p < 15) {
#pragma unroll
                for (int t = 0; t < 2; t++)
#pragma unroll
                    for (int r = 0; r < 4; r++) {
                        float v = dt[t][r] * acc[t][r];
                        hd[t][r] += v;
                        Aw[fb[t] + r * 8] = f2bf(v);
                    }
            } else {
#pragma unroll
                for (int t = 0; t < 2; t++)
#pragma unroll
                    for (int r = 0; r < 4; r++) hd[t][r] += dt[t][r] * acc[t][r];
            }
        } else {                // wh phase: s = drelu*(curr@wh^T)
#pragma unroll
            for (int t = 0; t < 2; t++)
#pragma unroll
                for (int r = 0; r < 4; r++)
                    Aw[fb[t] + r * 8] = f2bf(dr[t][r] * acc[t][r]);
        }
        if (p < 15) __syncthreads();  // one barrier per phase (double-buffer => no lapping)
    }

#pragma unroll
    for (int t = 0; t < 2; t++) {
        const int c = (w * 2 + t) * 16 + col2;
#pragma unroll
        for (int r = 0; r < 4; r++)
            outp[(size_t)(bt * 16 + kq * 4 + r) * HH + c] = hd[t][r];
    }
}

// ---------------------------------------------------------------------------
extern "C" void kernel_launch(void* const* d_in, const int* in_sizes, int n_in,
                              void* d_out, int out_size, void* d_ws, size_t ws_size,
                              hipStream_t stream) {
    const float* tg = (const float*)d_in[0];
    const float* h = (const float*)d_in[1];
    const float* coeffs = (const float*)d_in[2];
    const float* dcoeffs = (const float*)d_in[3];
    const float* tobs = (const float*)d_in[4];
    const float* wx = (const float*)d_in[5];
    const float* wh = (const float*)d_in[6];
    const float* wout = (const float*)d_in[7];
    const float* b0g = (const float*)d_in[8];
    const float* b1g = (const float*)d_in[9];
    float* outp = (float*)d_out;

    char* ws = (char*)d_ws;
    unsigned short* whp    = (unsigned short*)(ws + 0);        // 512KB packed bf16
    unsigned short* wop    = (unsigned short*)(ws + 524288);   // 512KB
    unsigned short* wxp    = (unsigned short*)(ws + 1048576);  // 64KB
    unsigned short* hb     = (unsigned short*)(ws + 1114112);  // 256KB
    unsigned short* xb     = (unsigned short*)(ws + 1376256);  // 32KB
    unsigned short* xdb    = (unsigned short*)(ws + 1409024);  // 32KB
    unsigned short* relu_b = (unsigned short*)(ws + 1441792);  // 256KB
    unsigned short* s0_b   = (unsigned short*)(ws + 1703936);  // 256KB
    float* drelu_f         = (float*)(ws + 1966080);           // 512KB
    float* dtanh_f         = (float*)(ws + 2490368);           // 512KB
    unsigned short* curr_b = (unsigned short*)(ws + 3014656);  // 256KB (A-frag)
    float* curr0_f         = (float*)(ws + 3276800);           // 512KB

    k_pack<<<2752, 256, 0, stream>>>(wh, wout, wx, h, coeffs, dcoeffs, tobs, tg,
                                     whp, wop, wxp, hb, xb, xdb);
    k_l1<<<dim3(8, 8), 256, 0, stream>>>(whp, wxp, hb, xb, xdb, b0g, relu_b, drelu_f, s0_b);
    k_th<<<dim3(8, 8), 256, 0, stream>>>(wop, relu_b, s0_b, b1g, dtanh_f, curr_b, curr0_f);
    k_loop5<<<16, 1024, 0, stream>>>(whp, wop, curr_b, curr0_f, drelu_f, dtanh_f, outp);
}

// Round 6
// 171.083 us; speedup vs baseline: 1.9747x; 1.0627x over previous
//
#include <hip/hip_runtime.h>

// Problem constants
#define BB 256   // batch
#define HH 512   // hidden
#define CC 64    // spline channels
#define NN 100   // time knots
#define KT 8     // K_TERMS

typedef short s16x8 __attribute__((ext_vector_type(8)));
typedef float f32x4 __attribute__((ext_vector_type(4)));

#define MFMA16(a, b, c) __builtin_amdgcn_mfma_f32_16x16x32_bf16((a), (b), (c), 0, 0, 0)

static __device__ __forceinline__ unsigned short f2bf(float f) {
    union { float f; unsigned int u; } v; v.f = f;
    unsigned int r = v.u + 0x7FFFu + ((v.u >> 16) & 1u);  // RNE
    return (unsigned short)(r >> 16);
}

// ---------------------------------------------------------------------------
// A-frag layout for a 16-row x 512-col bf16 activation tile t (8192 halfwords):
//   F[t*8192 + g*512 + lane*8 + e] = M[lane&15][g*32 + (lane>>4)*8 + e]
// K-half s (cols [s*256,(s+1)*256)) = halfwords [s*4096,(s+1)*4096): contiguous.
// ---------------------------------------------------------------------------

// ---------------------------------------------------------------------------
// k_pack: weight bf16 conversion into MFMA-frag-packed layout + h conversion +
// cubic spline evaluation (x, xdot).  (Round-1 proven version.)
// ---------------------------------------------------------------------------
__global__ void k_pack(const float* __restrict__ wh, const float* __restrict__ wout,
                       const float* __restrict__ wx, const float* __restrict__ h,
                       const float* __restrict__ coeffs, const float* __restrict__ dcoeffs,
                       const float* __restrict__ tobs, const float* __restrict__ tg,
                       unsigned short* __restrict__ whp, unsigned short* __restrict__ wop,
                       unsigned short* __restrict__ wxp, unsigned short* __restrict__ hb,
                       unsigned short* __restrict__ xb, unsigned short* __restrict__ xdb) {
    int gid = blockIdx.x * 256 + threadIdx.x;
    if (gid < 524288) {                       // wh / wout packed (262144 each)
        const float* src = (gid < 262144) ? wh : wout;
        unsigned short* dst = (gid < 262144) ? whp : wop;
        int p = gid & 262143;
        int e = p & 7, lane = (p >> 3) & 63, g = (p >> 9) & 15, cg = (p >> 13) & 1, w = p >> 14;
        int row = w * 32 + cg * 16 + (lane & 15);
        int k = g * 32 + (lane >> 4) * 8 + e;
        dst[p] = f2bf(src[row * HH + k]);
    } else if (gid < 557056) {                // wx packed (32768)
        int p = gid - 524288;
        int e = p & 7, lane = (p >> 3) & 63, g = (p >> 9) & 1, cg = (p >> 10) & 1, w = p >> 11;
        int row = w * 32 + cg * 16 + (lane & 15);
        int k = g * 32 + (lane >> 4) * 8 + e;
        wxp[p] = f2bf(wx[row * CC + k]);
    } else if (gid < 688128) {                // h -> bf16 row-major (131072)
        int p = gid - 557056;
        hb[p] = f2bf(h[p]);
    } else if (gid < 704512) {                // spline eval: x, xdot (16384)
        int p = gid - 688128;
        int b = p >> 6, c = p & 63;
        float t = tg[0];
        int cntv = 0;
        for (int n = 0; n < NN; n++) cntv += (tobs[n] <= t) ? 1 : 0;
        int idx = cntv - 1;
        idx = idx < 0 ? 0 : (idx > NN - 2 ? NN - 2 : idx);  // clip to [0, 98]
        float dt = t - tobs[idx];
        const float* cb = coeffs + ((size_t)(b * (NN - 1) + idx) * 4) * CC + c;
        float xv = cb[0] + dt * (cb[CC] + dt * (cb[2 * CC] + dt * cb[3 * CC]));
        const float* db = dcoeffs + ((size_t)(b * (NN - 1) + idx) * 4) * CC + c;
        float xd = db[0] + dt * (db[CC] + dt * (db[2 * CC] + dt * db[3 * CC]));
        xb[p] = f2bf(xv);
        xdb[p] = f2bf(xd);
    }
}

// ---------------------------------------------------------------------------
// k_l1: l1 = x@wx^T + h@wh^T + b0 -> relu(bf16), drelu=sigmoid(l1) (f32)
//       fused: v = xdot@wx^T ; s0 = drelu*v (bf16)          (round-1 proven)
// ---------------------------------------------------------------------------
__global__ void k_l1(const unsigned short* __restrict__ whp, const unsigned short* __restrict__ wxp,
                     const unsigned short* __restrict__ hb, const unsigned short* __restrict__ xb,
                     const unsigned short* __restrict__ xdb, const float* __restrict__ b0g,
                     unsigned short* __restrict__ relu_b, float* __restrict__ drelu_f,
                     unsigned short* __restrict__ s0_b) {
    __shared__ unsigned short sh[32][520];
    __shared__ unsigned short sx[32][72];
    __shared__ unsigned short sxd[32][72];
    int tid = threadIdx.x;
    int b0 = blockIdx.x * 32;
    int it = blockIdx.y;
    for (int idx = tid; idx < 32 * 64; idx += 256) {
        int r = idx >> 6, c8 = idx & 63;
        *(int4*)&sh[r][c8 * 8] = *(const int4*)&hb[(b0 + r) * HH + c8 * 8];
    }
    for (int idx = tid; idx < 32 * 8; idx += 256) {
        int r = idx >> 3, c8 = idx & 7;
        *(int4*)&sx[r][c8 * 8] = *(const int4*)&xb[(b0 + r) * CC + c8 * 8];
        *(int4*)&sxd[r][c8 * 8] = *(const int4*)&xdb[(b0 + r) * CC + c8 * 8];
    }
    __syncthreads();
    int wv = tid >> 6, lane = tid & 63, col = lane & 15, kq = lane >> 4;
    int isub = it * 64 + wv * 16;
    int wpk = isub >> 5, cg = (isub >> 4) & 1;
    f32x4 acc0 = {0.f, 0.f, 0.f, 0.f}, acc1 = {0.f, 0.f, 0.f, 0.f};
    f32x4 vac0 = {0.f, 0.f, 0.f, 0.f}, vac1 = {0.f, 0.f, 0.f, 0.f};
    const s16x8* whfrag = (const s16x8*)whp + (size_t)((wpk * 2 + cg) * 16) * 64 + lane;
#pragma unroll
    for (int g = 0; g < 16; g++) {
        s16x8 bf = whfrag[g * 64];
        s16x8 a0 = *(const s16x8*)&sh[col][g * 32 + kq * 8];
        s16x8 a1 = *(const s16x8*)&sh[16 + col][g * 32 + kq * 8];
        acc0 = MFMA16(a0, bf, acc0);
        acc1 = MFMA16(a1, bf, acc1);
    }
    const s16x8* wxfrag = (const s16x8*)wxp + (size_t)((wpk * 2 + cg) * 2) * 64 + lane;
#pragma unroll
    for (int g = 0; g < 2; g++) {
        s16x8 bf = wxfrag[g * 64];
        s16x8 a0 = *(const s16x8*)&sx[col][g * 32 + kq * 8];
        s16x8 a1 = *(const s16x8*)&sx[16 + col][g * 32 + kq * 8];
        acc0 = MFMA16(a0, bf, acc0);
        acc1 = MFMA16(a1, bf, acc1);
        s16x8 d0 = *(const s16x8*)&sxd[col][g * 32 + kq * 8];
        s16x8 d1 = *(const s16x8*)&sxd[16 + col][g * 32 + kq * 8];
        vac0 = MFMA16(d0, bf, vac0);
        vac1 = MFMA16(d1, bf, vac1);
    }
    int ic = isub + col;
    float bias = b0g[ic];
#pragma unroll
    for (int r = 0; r < 4; r++) {
        int bb = b0 + kq * 4 + r;
        float l1a = acc0[r] + bias;
        float dra = 1.f / (1.f + expf(-l1a));
        relu_b[bb * HH + ic] = f2bf(fmaxf(l1a, 0.f));
        drelu_f[bb * HH + ic] = dra;
        s0_b[bb * HH + ic] = f2bf(dra * vac0[r]);
        float l1b = acc1[r] + bias;
        float drb = 1.f / (1.f + expf(-l1b));
        relu_b[(bb + 16) * HH + ic] = f2bf(fmaxf(l1b, 0.f));
        drelu_f[(bb + 16) * HH + ic] = drb;
        s0_b[(bb + 16) * HH + ic] = f2bf(drb * vac1[r]);
    }
}

// ---------------------------------------------------------------------------
// k_th: z = relu@wout^T + b1 -> th=tanh(z), dtanh=1-th^2 (f32)
//       fused: curr0 = dtanh * (s0@wout^T); stores curr0 f32 row-major and
//       bf16 A-frag. Also zeroes the loop kernel's sync flags (block 0,0).
// ---------------------------------------------------------------------------
__global__ void k_th(const unsigned short* __restrict__ wop, const unsigned short* __restrict__ relu_b,
                     const unsigned short* __restrict__ s0_b, const float* __restrict__ b1g,
                     float* __restrict__ dtanh_f, unsigned short* __restrict__ curr_b,
                     float* __restrict__ curr0_f, unsigned int* __restrict__ flg) {
    __shared__ unsigned short sr[32][520];
    __shared__ unsigned short ss0[32][520];
    int tid = threadIdx.x;
    if (blockIdx.x == 0 && blockIdx.y == 0) {  // zero 512 flag words (32 flags, 64B stride)
        flg[tid] = 0u;
        flg[tid + 256] = 0u;
    }
    int b0 = blockIdx.x * 32;
    int it = blockIdx.y;
    for (int idx = tid; idx < 32 * 64; idx += 256) {
        int r = idx >> 6, c8 = idx & 63;
        *(int4*)&sr[r][c8 * 8] = *(const int4*)&relu_b[(b0 + r) * HH + c8 * 8];
        *(int4*)&ss0[r][c8 * 8] = *(const int4*)&s0_b[(b0 + r) * HH + c8 * 8];
    }
    __syncthreads();
    int wv = tid >> 6, lane = tid & 63, col = lane & 15, kq = lane >> 4;
    int isub = it * 64 + wv * 16;
    int wpk = isub >> 5, cg = (isub >> 4) & 1;
    f32x4 acc0 = {0.f, 0.f, 0.f, 0.f}, acc1 = {0.f, 0.f, 0.f, 0.f};
    f32x4 cac0 = {0.f, 0.f, 0.f, 0.f}, cac1 = {0.f, 0.f, 0.f, 0.f};
    const s16x8* wofrag = (const s16x8*)wop + (size_t)((wpk * 2 + cg) * 16) * 64 + lane;
#pragma unroll
    for (int g = 0; g < 16; g++) {
        s16x8 bf = wofrag[g * 64];
        s16x8 a0 = *(const s16x8*)&sr[col][g * 32 + kq * 8];
        s16x8 a1 = *(const s16x8*)&sr[16 + col][g * 32 + kq * 8];
        acc0 = MFMA16(a0, bf, acc0);
        acc1 = MFMA16(a1, bf, acc1);
        s16x8 p0 = *(const s16x8*)&ss0[col][g * 32 + kq * 8];
        s16x8 p1 = *(const s16x8*)&ss0[16 + col][g * 32 + kq * 8];
        cac0 = MFMA16(p0, bf, cac0);
        cac1 = MFMA16(p1, bf, cac1);
    }
    int ic = isub + col;
    float bias = b1g[ic];
    int fc = (ic >> 5) * 512 + (ic & 7) + (((ic >> 3) & 3) << 7);
#pragma unroll
    for (int r = 0; r < 4; r++) {
        int bb = b0 + kq * 4 + r;
        int row8 = (kq * 4 + r) * 8;
        float th_a = tanhf(acc0[r] + bias);
        float dta = 1.f - th_a * th_a;
        float c0a = dta * cac0[r];
        dtanh_f[bb * HH + ic] = dta;
        curr_b[(bb >> 4) * 8192 + fc + row8] = f2bf(c0a);
        curr0_f[bb * HH + ic] = c0a;
        float th_b = tanhf(acc1[r] + bias);
        float dtb = 1.f - th_b * th_b;
        float c0b = dtb * cac1[r];
        dtanh_f[(bb + 16) * HH + ic] = dtb;
        curr_b[((bb + 16) >> 4) * 8192 + fc + row8] = f2bf(c0b);
        curr0_f[(bb + 16) * HH + ic] = c0b;
    }
}

// ---------------------------------------------------------------------------
// k_loop6: Neumann loop split 2-ways per chain. 32 blocks x 512 threads:
// block = (s<<4)|c handles chain c (16 batch rows), column half s (256 cols).
// Per phase each block streams only ITS 256KB weight half (vs 512KB in
// k_loop3/5 -> ~2.3us at the measured ~47 B/cy/CU L2 link) and exchanges its
// 8KB half of next-curr with its partner via agent-scope sc1 atomics:
//  - producer: LDS epilogue -> barrier -> coalesced u64 RELAXED-atomic copy to
//    xch[c][p&1][s] -> barrier (vmcnt drain) -> tid0 RELEASE flag = p+1.
//  - consumer: tid0 RELAXED spin (no per-poll buffer_inv -> doesn't blow away
//    co-resident blocks' L2 weight stream) -> barrier -> u64 RELAXED-atomic
//    stage of partner half into LDS -> barrier -> GEMM.
// Slot overwrite at phase p is safe: fpr>=p implies partner already staged
// my p-2 data (its p-1 prologue precedes its p-1 flag). Arithmetic identical
// to k_loop5 (same MFMA tiling + K order) => absmax unchanged.
// Pair (c, 16+c) lands on the same XCD under %8 dispatch (speed, not
// correctness: agent-scope sc1 ops are placement-independent).
// ---------------------------------------------------------------------------
__global__ __launch_bounds__(512) void k_loop6(
    const unsigned short* __restrict__ whp, const unsigned short* __restrict__ wop,
    const unsigned short* __restrict__ curr_b, const float* __restrict__ curr0_f,
    const float* __restrict__ drelu_f, const float* __restrict__ dtanh_f,
    unsigned short* __restrict__ xch, unsigned int* flg,
    float* __restrict__ outp) {
    __shared__ __align__(16) unsigned short sa[2][8192];  // ping-pong A-frag (16KB each)
    const int tid = threadIdx.x;
    const int w = tid >> 6, lane = tid & 63;
    const int col2 = lane & 15, kq = lane >> 4;
    const int c = blockIdx.x & 15;   // chain (batch tile)
    const int s = blockIdx.x >> 4;   // column half

    // stage curr0 full tile (A-frag from k_th) into sa[0]: 1024 int4
    {
        const int4* src = (const int4*)(curr_b + (size_t)c * 8192);
        int4* dst = (int4*)&sa[0][0];
        dst[tid] = src[tid];
        dst[tid + 512] = src[tid + 512];
    }

    // per-thread diagonals + h_dot accumulator: 2 col-tiles x 4 rows (my half)
    float dr[2][4], dt[2][4], hd[2][4];
#pragma unroll
    for (int t = 0; t < 2; t++) {
        const int cc = s * 256 + (w * 2 + t) * 16 + col2;
#pragma unroll
        for (int r = 0; r < 4; r++) {
            const int row = c * 16 + kq * 4 + r;
            dr[t][r] = drelu_f[row * HH + cc];
            dt[t][r] = dtanh_f[row * HH + cc];
            hd[t][r] = curr0_f[row * HH + cc];
        }
    }

    // LDS halfword index (r=0) within my half for (row m=kq*4+r, local tile ct=w*2+t)
    int fbl[2];
#pragma unroll
    for (int t = 0; t < 2; t++)
        fbl[t] = w * 512 + (col2 & 7) + (((t * 2 + (col2 >> 3)) & 3) << 7) + kq * 32;
    const int myhalf = s * 4096;
    const int phalf = (1 - s) * 4096;

    // wave's B-frag base within my half: absolute tiles s*16 + w*2 + t
    const s16x8* wlh = (const s16x8*)whp + (size_t)(s * 16 + w * 2) * 1024 + lane;
    const s16x8* wlo = (const s16x8*)wop + (size_t)(s * 16 + w * 2) * 1024 + lane;
    const unsigned short* A0 = &sa[0][lane * 8];
    const unsigned short* A1 = &sa[1][lane * 8];
    unsigned int* fme = flg + (s * 16 + c) * 16;         // own 64B line
    unsigned int* fpr = flg + ((1 - s) * 16 + c) * 16;

    __syncthreads();  // curr0 staged

    for (int p = 0; p < 16; p++) {
        if (p) {
            if (tid == 0) {
                while (__hip_atomic_load(fpr, __ATOMIC_RELAXED, __HIP_MEMORY_SCOPE_AGENT)
                       < (unsigned)p) { __builtin_amdgcn_s_sleep(1); }
            }
            __syncthreads();  // flag observed
            // stage partner half of curr_p (sc1 loads bypass stale caches)
            const unsigned long long* gsrc = (const unsigned long long*)
                (xch + ((size_t)(c * 2 + ((p - 1) & 1)) * 2 + (1 - s)) * 4096);
            unsigned long long v0 = __hip_atomic_load(&gsrc[tid], __ATOMIC_RELAXED, __HIP_MEMORY_SCOPE_AGENT);
            unsigned long long v1 = __hip_atomic_load(&gsrc[tid + 512], __ATOMIC_RELAXED, __HIP_MEMORY_SCOPE_AGENT);
            unsigned long long* ld = (unsigned long long*)&sa[p & 1][phalf];
            ld[tid] = v0;
            ld[tid + 512] = v1;
            __syncthreads();  // staging visible
        }
        const s16x8* wl = (p & 1) ? wlo : wlh;          // even: wh, odd: wout
        const unsigned short* Ar = (p & 1) ? A1 : A0;   // read sa[p&1]
        f32x4 acc[2] = {{0.f, 0.f, 0.f, 0.f}, {0.f, 0.f, 0.f, 0.f}};
        s16x8 bfr[2][2];
#pragma unroll
        for (int t = 0; t < 2; t++) bfr[0][t] = wl[t * 1024];
#pragma unroll
        for (int g = 0; g < 16; g++) {
            if (g < 15) {
#pragma unroll
                for (int t = 0; t < 2; t++) bfr[(g + 1) & 1][t] = wl[t * 1024 + (g + 1) * 64];
            }
            const s16x8 a = *(const s16x8*)(Ar + (size_t)g * 512);
#pragma unroll
            for (int t = 0; t < 2; t++) acc[t] = MFMA16(a, bfr[g & 1][t], acc[t]);
        }
        unsigned short* Aw = &sa[(p + 1) & 1][0];       // write the other buffer
        if (p & 1) {            // wout phase: curr' = dtanh*(s@wout^T); h_dot += curr'
            if (p < 15) {
#pragma unroll
                for (int t = 0; t < 2; t++)
#pragma unroll
                    for (int r = 0; r < 4; r++) {
                        float v = dt[t][r] * acc[t][r];
                        hd[t][r] += v;
                        Aw[myhalf + fbl[t] + r * 8] = f2bf(v);
                    }
            } else {
#pragma unroll
                for (int t = 0; t < 2; t++)
#pragma unroll
                    for (int r = 0; r < 4; r++) hd[t][r] += dt[t][r] * acc[t][r];
            }
        } else {                // wh phase: s = drelu*(curr@wh^T)
#pragma unroll
            for (int t = 0; t < 2; t++)
#pragma unroll
                for (int r = 0; r < 4; r++)
                    Aw[myhalf + fbl[t] + r * 8] = f2bf(dr[t][r] * acc[t][r]);
        }
        if (p < 15) {
            __syncthreads();    // my-half LDS writes visible block-wide
            // coalesced export of my half (sc1 stores bypass L2 -> cheap wbl2)
            unsigned long long* gdst = (unsigned long long*)
                (xch + ((size_t)(c * 2 + (p & 1)) * 2 + s) * 4096);
            const unsigned long long* lsrc = (const unsigned long long*)&sa[(p + 1) & 1][myhalf];
            __hip_atomic_store(&gdst[tid], lsrc[tid], __ATOMIC_RELAXED, __HIP_MEMORY_SCOPE_AGENT);
            __hip_atomic_store(&gdst[tid + 512], lsrc[tid + 512], __ATOMIC_RELAXED, __HIP_MEMORY_SCOPE_AGENT);
            __syncthreads();    // all waves' exports drained (vmcnt(0) at barrier)
            if (tid == 0)
                __hip_atomic_store(fme, (unsigned)(p + 1), __ATOMIC_RELEASE, __HIP_MEMORY_SCOPE_AGENT);
        }
    }

#pragma unroll
    for (int t = 0; t < 2; t++) {
        const int cc = s * 256 + (w * 2 + t) * 16 + col2;
#pragma unroll
        for (int r = 0; r < 4; r++)
            outp[(size_t)(c * 16 + kq * 4 + r) * HH + cc] = hd[t][r];
    }
}

// ---------------------------------------------------------------------------
extern "C" void kernel_launch(void* const* d_in, const int* in_sizes, int n_in,
                              void* d_out, int out_size, void* d_ws, size_t ws_size,
                              hipStream_t stream) {
    const float* tg = (const float*)d_in[0];
    const float* h = (const float*)d_in[1];
    const float* coeffs = (const float*)d_in[2];
    const float* dcoeffs = (const float*)d_in[3];
    const float* tobs = (const float*)d_in[4];
    const float* wx = (const float*)d_in[5];
    const float* wh = (const float*)d_in[6];
    const float* wout = (const float*)d_in[7];
    const float* b0g = (const float*)d_in[8];
    const float* b1g = (const float*)d_in[9];
    float* outp = (float*)d_out;

    char* ws = (char*)d_ws;
    unsigned short* whp    = (unsigned short*)(ws + 0);        // 512KB packed bf16
    unsigned short* wop    = (unsigned short*)(ws + 524288);   // 512KB
    unsigned short* wxp    = (unsigned short*)(ws + 1048576);  // 64KB
    unsigned short* hb     = (unsigned short*)(ws + 1114112);  // 256KB
    unsigned short* xb     = (unsigned short*)(ws + 1376256);  // 32KB
    unsigned short* xdb    = (unsigned short*)(ws + 1409024);  // 32KB
    unsigned short* relu_b = (unsigned short*)(ws + 1441792);  // 256KB (dead after k_th)
    unsigned short* s0_b   = (unsigned short*)(ws + 1703936);  // 256KB (dead after k_th)
    float* drelu_f         = (float*)(ws + 1966080);           // 512KB
    float* dtanh_f         = (float*)(ws + 2490368);           // 512KB
    unsigned short* curr_b = (unsigned short*)(ws + 3014656);  // 256KB (A-frag)
    float* curr0_f         = (float*)(ws + 3276800);           // 512KB
    unsigned short* xch    = (unsigned short*)(ws + 1441792);  // 512KB exchange (overlays relu/s0)
    unsigned int* flg      = (unsigned int*)(ws + 3801088);    // 2KB flags

    k_pack<<<2752, 256, 0, stream>>>(wh, wout, wx, h, coeffs, dcoeffs, tobs, tg,
                                     whp, wop, wxp, hb, xb, xdb);
    k_l1<<<dim3(8, 8), 256, 0, stream>>>(whp, wxp, hb, xb, xdb, b0g, relu_b, drelu_f, s0_b);
    k_th<<<dim3(8, 8), 256, 0, stream>>>(wop, relu_b, s0_b, b1g, dtanh_f, curr_b, curr0_f, flg);
    k_loop6<<<32, 512, 0, stream>>>(whp, wop, curr_b, curr0_f, drelu_f, dtanh_f, xch, flg, outp);
}